// Round 2
// baseline (4185.049 us; speedup 1.0000x reference)
//
#include <hip/hip_runtime.h>

typedef unsigned int u32;
typedef unsigned short u16;
typedef unsigned long long u64;

// ---------------- problem constants ----------------
// B=2048, CIN=256, NH=512, NF=112, K=112, NL=50, MC=100, NOUT=200
// out (f32 elements): c_prob [2048,112,100] | y [2048,200] | c_hard [2048,112,100]
#define YOFF  22937600ull
#define CHOFF 23347200ull

// workspace offsets (bytes) — total ~9.3 MB
#define OFF_HA    0ull          // 2048*512 f32 = 4,194,304 B
#define OFF_HB    4194304ull    // 2048*512 f32
#define OFF_INTER 8388608ull    // 2048*112 f32 = 917,504 B

// ---------------- threefry2x32 (JAX-compatible, partitionable stream) ----------------
__host__ __device__ inline u32 rotl32_(u32 x, int r) { return (x << r) | (x >> (32 - r)); }
__host__ __device__ inline void tf2x32(u32 k0, u32 k1, u32 c0, u32 c1, u32& o0, u32& o1) {
  u32 ks0 = k0, ks1 = k1, ks2 = k0 ^ k1 ^ 0x1BD11BDAu;
  u32 x0 = c0 + ks0, x1 = c1 + ks1;
  const int RA[4] = {13, 15, 26, 6}, RB[4] = {17, 29, 16, 24};
  for (int i = 0; i < 5; ++i) {
    const int* R = (i & 1) ? RB : RA;
    for (int j = 0; j < 4; ++j) { x0 += x1; x1 = rotl32_(x1, R[j]); x1 ^= x0; }
    switch (i) {
      case 0: x0 += ks1; x1 += ks2 + 1u; break;
      case 1: x0 += ks2; x1 += ks0 + 2u; break;
      case 2: x0 += ks0; x1 += ks1 + 3u; break;
      case 3: x0 += ks1; x1 += ks2 + 4u; break;
      case 4: x0 += ks2; x1 += ks0 + 5u; break;
    }
  }
  o0 = x0; o1 = x1;
}

struct SKeys { u32 v[224]; };  // per-step subkeys: sk_i = threefry(key_i, (0,1)); key_{i+1} = threefry(key_i, (0,0))

// ---------------- generic f32 GEMM: C = act(A@B + bias) ----------------
// 64x64 tile, BK=32, 256 threads, 4x4 per thread.
template <bool DO_LRELU>
__global__ __launch_bounds__(256) void gemm_bias(const float* __restrict__ A,
                                                 const float* __restrict__ Bm,
                                                 const float* __restrict__ bias,
                                                 float* __restrict__ C,
                                                 int M, int N, int K) {
  __shared__ float As[32][65];  // [k][m]
  __shared__ float Bs[32][65];  // [k][n]
  const int bm = blockIdx.y * 64, bn = blockIdx.x * 64;
  const int t = threadIdx.x;
  const int ty = t >> 4, tx = t & 15;
  float acc[4][4] = {};
  for (int k0 = 0; k0 < K; k0 += 32) {
#pragma unroll
    for (int l = 0; l < 2; ++l) {
      int e = l * 256 + t;                // < 512
      int m = e >> 3, k4 = e & 7;         // 64 rows x 8 float4
      float4 v = *(const float4*)(A + (size_t)(bm + m) * K + (k0 + k4 * 4));
      As[k4 * 4 + 0][m] = v.x; As[k4 * 4 + 1][m] = v.y;
      As[k4 * 4 + 2][m] = v.z; As[k4 * 4 + 3][m] = v.w;
    }
#pragma unroll
    for (int l = 0; l < 2; ++l) {
      int e = l * 256 + t;
      int k = e >> 4, n4 = e & 15;        // 32 k x 16 float4
      int gn = bn + n4 * 4;
      if (gn < N) {
        float4 v = *(const float4*)(Bm + (size_t)(k0 + k) * N + gn);
        Bs[k][n4 * 4 + 0] = v.x; Bs[k][n4 * 4 + 1] = v.y;
        Bs[k][n4 * 4 + 2] = v.z; Bs[k][n4 * 4 + 3] = v.w;
      } else {
        Bs[k][n4 * 4 + 0] = 0.f; Bs[k][n4 * 4 + 1] = 0.f;
        Bs[k][n4 * 4 + 2] = 0.f; Bs[k][n4 * 4 + 3] = 0.f;
      }
    }
    __syncthreads();
#pragma unroll
    for (int kk = 0; kk < 32; ++kk) {
      float a[4], b[4];
#pragma unroll
      for (int j = 0; j < 4; ++j) { a[j] = As[kk][ty * 4 + j]; b[j] = Bs[kk][tx * 4 + j]; }
#pragma unroll
      for (int i = 0; i < 4; ++i)
#pragma unroll
        for (int j = 0; j < 4; ++j) acc[i][j] = fmaf(a[i], b[j], acc[i][j]);
    }
    __syncthreads();
  }
#pragma unroll
  for (int i = 0; i < 4; ++i) {
#pragma unroll
    for (int j = 0; j < 4; ++j) {
      int m = bm + ty * 4 + i, n = bn + tx * 4 + j;
      if (n < N) {
        float s = acc[i][j] + bias[n];
        if (DO_LRELU) { if (s < 0.f) s = 0.01f * s; }
        C[(size_t)m * N + n] = s;
      }
    }
  }
}

// ---------------- base_i[b][h] = inter @ W1_i[:112,:] + b1_i  -> stored into out c_hard region ----------------
// block: 64 b x 50 h, fixed i = blockIdx.y. Stored at out[CHOFF + b*11200 + i*100 + h] (h<50),
// later consumed and overwritten by sample_kernel (which exclusively owns each b).
__global__ __launch_bounds__(256) void base_kernel(const float* __restrict__ inter,
                                                   const float* __restrict__ W1,
                                                   const float* __restrict__ pb1,
                                                   float* __restrict__ out) {
  __shared__ float As[112][65];  // [k][b]
  __shared__ float Ws[112][64];  // [k][h], zero-padded h>=50
  const int i = blockIdx.y;
  const int b0 = blockIdx.x * 64;
  const int t = threadIdx.x;
  const int ty = t >> 4, tx = t & 15;
#pragma unroll
  for (int l = 0; l < 7; ++l) {
    int e4 = l * 256 + t;               // < 1792 = 64 rows * 28 float4
    int k4 = e4 % 28, bs = e4 / 28;
    float4 v = *(const float4*)(inter + (size_t)(b0 + bs) * 112 + k4 * 4);
    As[k4 * 4 + 0][bs] = v.x; As[k4 * 4 + 1][bs] = v.y;
    As[k4 * 4 + 2][bs] = v.z; As[k4 * 4 + 3][bs] = v.w;
  }
#pragma unroll
  for (int l = 0; l < 28; ++l) {
    int e = l * 256 + t;                // < 7168 = 112*64
    int r = e >> 6, c = e & 63;
    Ws[r][c] = (c < 50) ? W1[(size_t)i * 11200 + r * 50 + c] : 0.f;
  }
  __syncthreads();
  float acc[4][4] = {};
  for (int kk = 0; kk < 112; ++kk) {
    float a[4], b[4];
#pragma unroll
    for (int j = 0; j < 4; ++j) { a[j] = As[kk][ty * 4 + j]; b[j] = Ws[kk][tx * 4 + j]; }
#pragma unroll
    for (int ii = 0; ii < 4; ++ii)
#pragma unroll
      for (int j = 0; j < 4; ++j) acc[ii][j] = fmaf(a[ii], b[j], acc[ii][j]);
  }
#pragma unroll
  for (int ii = 0; ii < 4; ++ii) {
#pragma unroll
    for (int j = 0; j < 4; ++j) {
      int b = b0 + ty * 4 + ii, h = tx * 4 + j;
      if (h < 50) {
        out[CHOFF + (size_t)b * 11200 + (size_t)i * 100 + h] = acc[ii][j] + pb1[i * 50 + h];
      }
    }
  }
}

// ---------------- sequential concept sampling ----------------
// One block owns b0=2*blockIdx.x and b1=b0+1 (200 pairs). 128 threads; t<100 active for compute,
// thread t handles pairs (b0,t) and (b1,t). History kept as register bitmasks.
// base rows are read from out[CHOFF...] into LDS, then overwritten with c_hard.
__global__ __launch_bounds__(128) void sample_kernel(const float* __restrict__ W1,
                                                     const float* __restrict__ W2,
                                                     const float* __restrict__ b2,
                                                     float* __restrict__ out, SKeys sks) {
  __shared__ __attribute__((aligned(16))) float Wrows[111][52];  // feedback rows for current step
  __shared__ float base2[2][52];
  __shared__ float w2row[52];
  const int t = threadIdx.x;
  const int b0 = blockIdx.x * 2, b1 = b0 + 1;
  u64 lo0 = 0, hi0 = 0, lo1 = 0, hi1 = 0;

  for (int i = 0; i < 112; ++i) {
    __syncthreads();  // previous step's LDS reads complete before restage
    const float* Wi = W1 + (size_t)i * 11200 + 5600;  // W1[i, 112:, :] contiguous
    for (int idx = t; idx < i * 50; idx += 128) {
      int r = idx / 50, h = idx - r * 50;
      Wrows[r][h] = Wi[idx];
    }
    if (t < 50) {
      base2[0][t] = out[CHOFF + (size_t)b0 * 11200 + (size_t)i * 100 + t];
      w2row[t]    = W2[i * 50 + t];
    } else if (t < 100) {
      base2[1][t - 50] = out[CHOFF + (size_t)b1 * 11200 + (size_t)i * 100 + (t - 50)];
    }
    __syncthreads();

    if (t < 100) {
      float acc0[52], acc1[52];
#pragma unroll
      for (int h = 0; h < 52; ++h) { acc0[h] = 0.f; acc1[h] = 0.f; }
      for (int r = 0; r < i; ++r) {
        float c0 = (((r < 64) ? (lo0 >> r) : (hi0 >> (r - 64))) & 1ull) ? 1.f : 0.f;
        float c1 = (((r < 64) ? (lo1 >> r) : (hi1 >> (r - 64))) & 1ull) ? 1.f : 0.f;
        const float4* wr = (const float4*)(&Wrows[r][0]);
#pragma unroll
        for (int h4 = 0; h4 < 13; ++h4) {
          float4 w = wr[h4];
          acc0[h4 * 4 + 0] = fmaf(c0, w.x, acc0[h4 * 4 + 0]);
          acc0[h4 * 4 + 1] = fmaf(c0, w.y, acc0[h4 * 4 + 1]);
          acc0[h4 * 4 + 2] = fmaf(c0, w.z, acc0[h4 * 4 + 2]);
          acc0[h4 * 4 + 3] = fmaf(c0, w.w, acc0[h4 * 4 + 3]);
          acc1[h4 * 4 + 0] = fmaf(c1, w.x, acc1[h4 * 4 + 0]);
          acc1[h4 * 4 + 1] = fmaf(c1, w.y, acc1[h4 * 4 + 1]);
          acc1[h4 * 4 + 2] = fmaf(c1, w.z, acc1[h4 * 4 + 2]);
          acc1[h4 * 4 + 3] = fmaf(c1, w.w, acc1[h4 * 4 + 3]);
        }
      }
      float s0 = 0.f, s1 = 0.f;
#pragma unroll
      for (int h = 0; h < 50; ++h) {
        float w2v = w2row[h];
        float v0 = acc0[h] + base2[0][h];
        if (v0 < 0.f) v0 = 0.01f * v0;
        s0 = fmaf(v0, w2v, s0);
        float v1 = acc1[h] + base2[1][h];
        if (v1 < 0.f) v1 = 0.01f * v1;
        s1 = fmaf(v1, w2v, s1);
      }
      float b2v = b2[i];
      float l0 = s0 + b2v, l1 = s1 + b2v;
      float p0 = 1.f / (1.f + expf(-l0));
      float p1 = 1.f / (1.f + expf(-l1));
      // JAX f32 uniform (partitionable): bits32 = o0^o1 of tf(sk_i, (0, flat_idx)); u = bitcast((bits>>9)|0x3F800000)-1
      u32 sk0 = sks.v[2 * i], sk1 = sks.v[2 * i + 1];
      u32 a0, a1;
      int j0 = b0 * 100 + t, j1 = b1 * 100 + t;
      tf2x32(sk0, sk1, 0u, (u32)j0, a0, a1);
      u32 bits0 = a0 ^ a1;
      u32 fb0 = (bits0 >> 9) | 0x3F800000u;
      float u0; __builtin_memcpy(&u0, &fb0, 4); u0 -= 1.f;
      tf2x32(sk0, sk1, 0u, (u32)j1, a0, a1);
      u32 bits1 = a0 ^ a1;
      u32 fb1 = (bits1 >> 9) | 0x3F800000u;
      float u1; __builtin_memcpy(&u1, &fb1, 4); u1 -= 1.f;
      int smp0 = (u0 < p0) ? 1 : 0;
      int smp1 = (u1 < p1) ? 1 : 0;
      size_t oc0 = (size_t)b0 * 11200 + (size_t)i * 100 + t;
      size_t oc1 = (size_t)b1 * 11200 + (size_t)i * 100 + t;
      out[oc0] = p0;
      out[oc1] = p1;
      out[CHOFF + oc0] = smp0 ? 1.0f : 0.0f;   // overwrites base cells (already staged in LDS)
      out[CHOFF + oc1] = smp1 ? 1.0f : 0.0f;
      if (smp0) { if (i < 64) lo0 |= 1ull << i; else hi0 |= 1ull << (i - 64); }
      if (smp1) { if (i < 64) lo1 |= 1ull << i; else hi1 |= 1ull << (i - 64); }
    }
  }
}

// ---------------- head: logits -> softmax -> mean over m -> log ----------------
// one block per b; 256 threads
__global__ __launch_bounds__(256) void head_kernel(const float* __restrict__ HW,
                                                   const float* __restrict__ hb,
                                                   float* __restrict__ out) {
  __shared__ unsigned char cS[100][116];
  __shared__ float lgS[50][201];
  const int b = blockIdx.x;
  const int t = threadIdx.x;
  for (int e = t; e < 11200; e += 256) {
    int k = e / 100, m = e - k * 100;
    cS[m][k] = (out[CHOFF + (size_t)b * 11200 + (size_t)k * 100 + m] != 0.f) ? 1 : 0;
  }
  __syncthreads();
  float pacc = 0.f;
  for (int mh = 0; mh < 2; ++mh) {
    for (int l = 0; l < 3; ++l) {
      int tile = l * 256 + t;
      if (tile < 625) {                    // 25 o-chunks x 25 m-chunks
        int o0 = (tile % 25) * 8;
        int m0 = (tile / 25) * 2;
        float acc[2][8] = {};
        for (int k = 0; k < 112; ++k) {
          float4 wa = *(const float4*)(HW + (size_t)k * 200 + o0);
          float4 wb = *(const float4*)(HW + (size_t)k * 200 + o0 + 4);
          float w[8] = {wa.x, wa.y, wa.z, wa.w, wb.x, wb.y, wb.z, wb.w};
          float c0 = (float)cS[mh * 50 + m0][k];
          float c1 = (float)cS[mh * 50 + m0 + 1][k];
#pragma unroll
          for (int jo = 0; jo < 8; ++jo) {
            acc[0][jo] = fmaf(c0, w[jo], acc[0][jo]);
            acc[1][jo] = fmaf(c1, w[jo], acc[1][jo]);
          }
        }
#pragma unroll
        for (int im = 0; im < 2; ++im)
#pragma unroll
          for (int jo = 0; jo < 8; ++jo) {
            int o = o0 + jo;
            lgS[m0 + im][o] = acc[im][jo] + hb[o];
          }
      }
    }
    __syncthreads();
    if (t < 50) {
      int m = t;
      float mx = -3.0e38f;
      for (int o = 0; o < 200; ++o) mx = fmaxf(mx, lgS[m][o]);
      float s = 0.f;
      for (int o = 0; o < 200; ++o) {
        float e = expf(lgS[m][o] - mx);
        lgS[m][o] = e; s += e;
      }
      float inv = 1.f / s;
      for (int o = 0; o < 200; ++o) lgS[m][o] = lgS[m][o] * inv;
    }
    __syncthreads();
    if (t < 200) { for (int m = 0; m < 50; ++m) pacc += lgS[m][t]; }
    __syncthreads();
  }
  if (t < 200) {
    out[YOFF + (size_t)b * 200 + t] = logf(pacc / 100.f + 1e-6f);
  }
}

// ---------------- launcher ----------------
extern "C" void kernel_launch(void* const* d_in, const int* in_sizes, int n_in,
                              void* d_out, int out_size, void* d_ws, size_t ws_size,
                              hipStream_t stream) {
  const float* x    = (const float*)d_in[0];
  const float* Win  = (const float*)d_in[1];
  const float* bin  = (const float*)d_in[2];
  const float* Wh   = (const float*)d_in[3];
  const float* bh   = (const float*)d_in[4];
  const float* Wout = (const float*)d_in[5];
  const float* bout = (const float*)d_in[6];
  const float* pW1  = (const float*)d_in[7];
  const float* pb1  = (const float*)d_in[8];
  const float* pW2  = (const float*)d_in[9];
  const float* pb2  = (const float*)d_in[10];
  const float* hW   = (const float*)d_in[11];
  const float* hb   = (const float*)d_in[12];
  float* out = (float*)d_out;
  char* ws = (char*)d_ws;

  float* hA     = (float*)(ws + OFF_HA);
  float* hB     = (float*)(ws + OFF_HB);
  float* interB = (float*)(ws + OFF_INTER);

  gemm_bias<true ><<<dim3(8, 32), 256, 0, stream>>>(x,  Win,             bin,          hA,     2048, 512, 256);
  gemm_bias<true ><<<dim3(8, 32), 256, 0, stream>>>(hA, Wh + 0 * 262144, bh + 0 * 512, hB,     2048, 512, 512);
  gemm_bias<true ><<<dim3(8, 32), 256, 0, stream>>>(hB, Wh + 1 * 262144, bh + 1 * 512, hA,     2048, 512, 512);
  gemm_bias<true ><<<dim3(8, 32), 256, 0, stream>>>(hA, Wh + 2 * 262144, bh + 2 * 512, hB,     2048, 512, 512);
  gemm_bias<true ><<<dim3(8, 32), 256, 0, stream>>>(hB, Wh + 3 * 262144, bh + 3 * 512, hA,     2048, 512, 512);
  gemm_bias<false><<<dim3(2, 32), 256, 0, stream>>>(hA, Wout,            bout,         interB, 2048, 112, 512);

  base_kernel<<<dim3(32, 112), 256, 0, stream>>>(interB, pW1, pb1, out);

  // host-side key chain: key(42)=(0,42); partitionable split: key'=tf(key,(0,0)), sk=tf(key,(0,1))
  SKeys sks;
  {
    u32 k0 = 0u, k1 = 42u;
    for (int i = 0; i < 112; ++i) {
      u32 nk0, nk1, s0, s1;
      tf2x32(k0, k1, 0u, 0u, nk0, nk1);
      tf2x32(k0, k1, 0u, 1u, s0, s1);
      sks.v[2 * i] = s0; sks.v[2 * i + 1] = s1;
      k0 = nk0; k1 = nk1;
    }
  }
  sample_kernel<<<1024, 128, 0, stream>>>(pW1, pW2, pb2, out, sks);

  head_kernel<<<2048, 256, 0, stream>>>(hW, hb, out);
}

// Round 3
// 3714.243 us; speedup vs baseline: 1.1268x; 1.1268x over previous
//
#include <hip/hip_runtime.h>

typedef unsigned int u32;
typedef unsigned short u16;
typedef unsigned long long u64;

// ---------------- problem constants ----------------
// B=2048, CIN=256, NH=512, NF=112, K=112, NL=50, MC=100, NOUT=200
// out (f32 elements): c_prob [2048,112,100] | y [2048,200] | c_hard [2048,112,100]
#define YOFF  22937600ull
#define CHOFF 23347200ull

// workspace offsets (bytes) — total ~9.3 MB
#define OFF_HA    0ull          // 2048*512 f32 = 4,194,304 B
#define OFF_HB    4194304ull    // 2048*512 f32
#define OFF_INTER 8388608ull    // 2048*112 f32 = 917,504 B

// ---------------- threefry2x32 (JAX-compatible, partitionable stream) ----------------
__host__ __device__ inline u32 rotl32_(u32 x, int r) { return (x << r) | (x >> (32 - r)); }
__host__ __device__ inline void tf2x32(u32 k0, u32 k1, u32 c0, u32 c1, u32& o0, u32& o1) {
  u32 ks0 = k0, ks1 = k1, ks2 = k0 ^ k1 ^ 0x1BD11BDAu;
  u32 x0 = c0 + ks0, x1 = c1 + ks1;
  const int RA[4] = {13, 15, 26, 6}, RB[4] = {17, 29, 16, 24};
  for (int i = 0; i < 5; ++i) {
    const int* R = (i & 1) ? RB : RA;
    for (int j = 0; j < 4; ++j) { x0 += x1; x1 = rotl32_(x1, R[j]); x1 ^= x0; }
    switch (i) {
      case 0: x0 += ks1; x1 += ks2 + 1u; break;
      case 1: x0 += ks2; x1 += ks0 + 2u; break;
      case 2: x0 += ks0; x1 += ks1 + 3u; break;
      case 3: x0 += ks1; x1 += ks2 + 4u; break;
      case 4: x0 += ks2; x1 += ks0 + 5u; break;
    }
  }
  o0 = x0; o1 = x1;
}

struct SKeys { u32 v[224]; };  // per-step subkeys: sk_i = tf(key_i,(0,1)); key_{i+1} = tf(key_i,(0,0))

// ---------------- generic f32 GEMM: C = act(A@B + bias) ----------------
// 64x64 tile, BK=32, 256 threads, 4x4 per thread.
template <bool DO_LRELU>
__global__ __launch_bounds__(256) void gemm_bias(const float* __restrict__ A,
                                                 const float* __restrict__ Bm,
                                                 const float* __restrict__ bias,
                                                 float* __restrict__ C,
                                                 int M, int N, int K) {
  __shared__ float As[32][65];  // [k][m]
  __shared__ float Bs[32][65];  // [k][n]
  const int bm = blockIdx.y * 64, bn = blockIdx.x * 64;
  const int t = threadIdx.x;
  const int ty = t >> 4, tx = t & 15;
  float acc[4][4] = {};
  for (int k0 = 0; k0 < K; k0 += 32) {
#pragma unroll
    for (int l = 0; l < 2; ++l) {
      int e = l * 256 + t;                // < 512
      int m = e >> 3, k4 = e & 7;         // 64 rows x 8 float4
      float4 v = *(const float4*)(A + (size_t)(bm + m) * K + (k0 + k4 * 4));
      As[k4 * 4 + 0][m] = v.x; As[k4 * 4 + 1][m] = v.y;
      As[k4 * 4 + 2][m] = v.z; As[k4 * 4 + 3][m] = v.w;
    }
#pragma unroll
    for (int l = 0; l < 2; ++l) {
      int e = l * 256 + t;
      int k = e >> 4, n4 = e & 15;        // 32 k x 16 float4
      int gn = bn + n4 * 4;
      if (gn < N) {
        float4 v = *(const float4*)(Bm + (size_t)(k0 + k) * N + gn);
        Bs[k][n4 * 4 + 0] = v.x; Bs[k][n4 * 4 + 1] = v.y;
        Bs[k][n4 * 4 + 2] = v.z; Bs[k][n4 * 4 + 3] = v.w;
      } else {
        Bs[k][n4 * 4 + 0] = 0.f; Bs[k][n4 * 4 + 1] = 0.f;
        Bs[k][n4 * 4 + 2] = 0.f; Bs[k][n4 * 4 + 3] = 0.f;
      }
    }
    __syncthreads();
#pragma unroll
    for (int kk = 0; kk < 32; ++kk) {
      float a[4], b[4];
#pragma unroll
      for (int j = 0; j < 4; ++j) { a[j] = As[kk][ty * 4 + j]; b[j] = Bs[kk][tx * 4 + j]; }
#pragma unroll
      for (int i = 0; i < 4; ++i)
#pragma unroll
        for (int j = 0; j < 4; ++j) acc[i][j] = fmaf(a[i], b[j], acc[i][j]);
    }
    __syncthreads();
  }
#pragma unroll
  for (int i = 0; i < 4; ++i) {
#pragma unroll
    for (int j = 0; j < 4; ++j) {
      int m = bm + ty * 4 + i, n = bn + tx * 4 + j;
      if (n < N) {
        float s = acc[i][j] + bias[n];
        if (DO_LRELU) { if (s < 0.f) s = 0.01f * s; }
        C[(size_t)m * N + n] = s;
      }
    }
  }
}

// ---------------- base_i[b][h] = inter @ W1_i[:112,:] + b1_i  -> stored into out c_hard region ----------------
// block: 64 b x 50 h, fixed i = blockIdx.y. Stored at out[CHOFF + b*11200 + i*100 + h] (h<50),
// later consumed by sample_kernel and overwritten only at sample_kernel's end.
__global__ __launch_bounds__(256) void base_kernel(const float* __restrict__ inter,
                                                   const float* __restrict__ W1,
                                                   const float* __restrict__ pb1,
                                                   float* __restrict__ out) {
  __shared__ float As[112][65];  // [k][b]
  __shared__ float Ws[112][64];  // [k][h], zero-padded h>=50
  const int i = blockIdx.y;
  const int b0 = blockIdx.x * 64;
  const int t = threadIdx.x;
  const int ty = t >> 4, tx = t & 15;
#pragma unroll
  for (int l = 0; l < 7; ++l) {
    int e4 = l * 256 + t;               // < 1792 = 64 rows * 28 float4
    int k4 = e4 % 28, bs = e4 / 28;
    float4 v = *(const float4*)(inter + (size_t)(b0 + bs) * 112 + k4 * 4);
    As[k4 * 4 + 0][bs] = v.x; As[k4 * 4 + 1][bs] = v.y;
    As[k4 * 4 + 2][bs] = v.z; As[k4 * 4 + 3][bs] = v.w;
  }
#pragma unroll
  for (int l = 0; l < 28; ++l) {
    int e = l * 256 + t;                // < 7168 = 112*64
    int r = e >> 6, c = e & 63;
    Ws[r][c] = (c < 50) ? W1[(size_t)i * 11200 + r * 50 + c] : 0.f;
  }
  __syncthreads();
  float acc[4][4] = {};
  for (int kk = 0; kk < 112; ++kk) {
    float a[4], b[4];
#pragma unroll
    for (int j = 0; j < 4; ++j) { a[j] = As[kk][ty * 4 + j]; b[j] = Ws[kk][tx * 4 + j]; }
#pragma unroll
    for (int ii = 0; ii < 4; ++ii)
#pragma unroll
      for (int j = 0; j < 4; ++j) acc[ii][j] = fmaf(a[ii], b[j], acc[ii][j]);
  }
#pragma unroll
  for (int ii = 0; ii < 4; ++ii) {
#pragma unroll
    for (int j = 0; j < 4; ++j) {
      int b = b0 + ty * 4 + ii, h = tx * 4 + j;
      if (h < 50) {
        out[CHOFF + (size_t)b * 11200 + (size_t)i * 100 + h] = acc[ii][j] + pb1[i * 50 + h];
      }
    }
  }
}

// ---------------- sequential concept sampling: ONE PAIR PER THREAD ----------------
// 512-thread blocks own exactly 5 whole batches (500 active threads). No LDS, no syncs.
// Feedback weights read at wave-uniform addresses -> scalar loads (s_load) + v_fmac v,s,v.
// History in 2 register u64 masks; c_hard written once at the end (mask expansion), so
// the base rows staged in out[CHOFF] stay intact until every thread of that batch is done
// (cell (b,i,m) is written ONLY by the thread owning pair (b,m)).
__global__ __launch_bounds__(512) void sample_kernel(const float* __restrict__ W1,
                                                     const float* __restrict__ W2,
                                                     const float* __restrict__ b2,
                                                     float* __restrict__ out, SKeys sks) {
  const int t = threadIdx.x;
  const int p = blockIdx.x * 500 + t;         // pair id = b*100 + m
  const bool active = (t < 500) && (p < 204800);
  const int b = p / 100;
  const int m = p - b * 100;
  const size_t rowbase = (size_t)b * 11200 + m;      // + i*100 -> c_prob/c_hard cell
  const float* __restrict__ baserow = out + CHOFF + (size_t)b * 11200;  // + i*100 + h
  u64 lo = 0, hi = 0;

  if (active) {
    for (int i = 0; i < 112; ++i) {
      const float* __restrict__ Wi = W1 + (size_t)i * 11200 + 5600;  // W1[i,112:,:], wave-uniform
      float acc[50];
#pragma unroll
      for (int h = 0; h < 50; ++h) acc[h] = 0.f;
      for (int r = 0; r < i; ++r) {
        float c = (((r < 64) ? (lo >> r) : (hi >> (r - 64))) & 1ull) ? 1.f : 0.f;
        const float* __restrict__ wr = Wi + r * 50;  // uniform address -> s_load
#pragma unroll
        for (int h = 0; h < 50; ++h) acc[h] = fmaf(c, wr[h], acc[h]);
      }
      // tail: v = lrelu(acc + base); s = dot(v, W2[i]); p = sigmoid(s + b2[i])
      const float* __restrict__ w2 = W2 + i * 50;    // uniform -> s_load
      const float* bs = baserow + (size_t)i * 100;
      float s = 0.f;
#pragma unroll
      for (int h = 0; h < 50; ++h) {
        float v = acc[h] + bs[h];
        if (v < 0.f) v = 0.01f * v;
        s = fmaf(v, w2[h], s);
      }
      float l = s + b2[i];
      float pr = 1.f / (1.f + expf(-l));
      // JAX f32 uniform (partitionable): bits = o0^o1 of tf(sk_i,(0,flat)); u = bitcast((bits>>9)|0x3F800000)-1
      u32 a0, a1;
      tf2x32(sks.v[2 * i], sks.v[2 * i + 1], 0u, (u32)p, a0, a1);
      u32 fb = ((a0 ^ a1) >> 9) | 0x3F800000u;
      float u; __builtin_memcpy(&u, &fb, 4); u -= 1.f;
      int smp = (u < pr) ? 1 : 0;
      out[rowbase + (size_t)i * 100] = pr;           // c_prob (owned cell)
      if (smp) { if (i < 64) lo |= 1ull << i; else hi |= 1ull << (i - 64); }
    }
    // expand history masks -> c_hard (overwrites base cells; every (b,i,m) cell has exactly one owner)
    for (int i = 0; i < 112; ++i) {
      u64 bit = (i < 64) ? (lo >> i) : (hi >> (i - 64));
      out[CHOFF + rowbase + (size_t)i * 100] = (bit & 1ull) ? 1.0f : 0.0f;
    }
  }
}

// ---------------- head: logits -> softmax -> mean over m -> log ----------------
// one block per b; 256 threads
__global__ __launch_bounds__(256) void head_kernel(const float* __restrict__ HW,
                                                   const float* __restrict__ hb,
                                                   float* __restrict__ out) {
  __shared__ unsigned char cS[100][116];
  __shared__ float lgS[50][201];
  const int b = blockIdx.x;
  const int t = threadIdx.x;
  for (int e = t; e < 11200; e += 256) {
    int k = e / 100, m = e - k * 100;
    cS[m][k] = (out[CHOFF + (size_t)b * 11200 + (size_t)k * 100 + m] != 0.f) ? 1 : 0;
  }
  __syncthreads();
  float pacc = 0.f;
  for (int mh = 0; mh < 2; ++mh) {
    for (int l = 0; l < 3; ++l) {
      int tile = l * 256 + t;
      if (tile < 625) {                    // 25 o-chunks x 25 m-chunks
        int o0 = (tile % 25) * 8;
        int m0 = (tile / 25) * 2;
        float acc[2][8] = {};
        for (int k = 0; k < 112; ++k) {
          float4 wa = *(const float4*)(HW + (size_t)k * 200 + o0);
          float4 wb = *(const float4*)(HW + (size_t)k * 200 + o0 + 4);
          float w[8] = {wa.x, wa.y, wa.z, wa.w, wb.x, wb.y, wb.z, wb.w};
          float c0 = (float)cS[mh * 50 + m0][k];
          float c1 = (float)cS[mh * 50 + m0 + 1][k];
#pragma unroll
          for (int jo = 0; jo < 8; ++jo) {
            acc[0][jo] = fmaf(c0, w[jo], acc[0][jo]);
            acc[1][jo] = fmaf(c1, w[jo], acc[1][jo]);
          }
        }
#pragma unroll
        for (int im = 0; im < 2; ++im)
#pragma unroll
          for (int jo = 0; jo < 8; ++jo) {
            int o = o0 + jo;
            lgS[m0 + im][o] = acc[im][jo] + hb[o];
          }
      }
    }
    __syncthreads();
    if (t < 50) {
      int m = t;
      float mx = -3.0e38f;
      for (int o = 0; o < 200; ++o) mx = fmaxf(mx, lgS[m][o]);
      float s = 0.f;
      for (int o = 0; o < 200; ++o) {
        float e = expf(lgS[m][o] - mx);
        lgS[m][o] = e; s += e;
      }
      float inv = 1.f / s;
      for (int o = 0; o < 200; ++o) lgS[m][o] = lgS[m][o] * inv;
    }
    __syncthreads();
    if (t < 200) { for (int m = 0; m < 50; ++m) pacc += lgS[m][t]; }
    __syncthreads();
  }
  if (t < 200) {
    out[YOFF + (size_t)b * 200 + t] = logf(pacc / 100.f + 1e-6f);
  }
}

// ---------------- launcher ----------------
extern "C" void kernel_launch(void* const* d_in, const int* in_sizes, int n_in,
                              void* d_out, int out_size, void* d_ws, size_t ws_size,
                              hipStream_t stream) {
  const float* x    = (const float*)d_in[0];
  const float* Win  = (const float*)d_in[1];
  const float* bin  = (const float*)d_in[2];
  const float* Wh   = (const float*)d_in[3];
  const float* bh   = (const float*)d_in[4];
  const float* Wout = (const float*)d_in[5];
  const float* bout = (const float*)d_in[6];
  const float* pW1  = (const float*)d_in[7];
  const float* pb1  = (const float*)d_in[8];
  const float* pW2  = (const float*)d_in[9];
  const float* pb2  = (const float*)d_in[10];
  const float* hW   = (const float*)d_in[11];
  const float* hb   = (const float*)d_in[12];
  float* out = (float*)d_out;
  char* ws = (char*)d_ws;

  float* hA     = (float*)(ws + OFF_HA);
  float* hB     = (float*)(ws + OFF_HB);
  float* interB = (float*)(ws + OFF_INTER);

  gemm_bias<true ><<<dim3(8, 32), 256, 0, stream>>>(x,  Win,             bin,          hA,     2048, 512, 256);
  gemm_bias<true ><<<dim3(8, 32), 256, 0, stream>>>(hA, Wh + 0 * 262144, bh + 0 * 512, hB,     2048, 512, 512);
  gemm_bias<true ><<<dim3(8, 32), 256, 0, stream>>>(hB, Wh + 1 * 262144, bh + 1 * 512, hA,     2048, 512, 512);
  gemm_bias<true ><<<dim3(8, 32), 256, 0, stream>>>(hA, Wh + 2 * 262144, bh + 2 * 512, hB,     2048, 512, 512);
  gemm_bias<true ><<<dim3(8, 32), 256, 0, stream>>>(hB, Wh + 3 * 262144, bh + 3 * 512, hA,     2048, 512, 512);
  gemm_bias<false><<<dim3(2, 32), 256, 0, stream>>>(hA, Wout,            bout,         interB, 2048, 112, 512);

  base_kernel<<<dim3(32, 112), 256, 0, stream>>>(interB, pW1, pb1, out);

  // host-side key chain: key(42)=(0,42); partitionable split: key'=tf(key,(0,0)), sk=tf(key,(0,1))
  SKeys sks;
  {
    u32 k0 = 0u, k1 = 42u;
    for (int i = 0; i < 112; ++i) {
      u32 nk0, nk1, s0, s1;
      tf2x32(k0, k1, 0u, 0u, nk0, nk1);
      tf2x32(k0, k1, 0u, 1u, s0, s1);
      sks.v[2 * i] = s0; sks.v[2 * i + 1] = s1;
      k0 = nk0; k1 = nk1;
    }
  }
  sample_kernel<<<410, 512, 0, stream>>>(pW1, pW2, pb2, out, sks);

  head_kernel<<<2048, 256, 0, stream>>>(hW, hb, out);
}